// Round 7
// baseline (613.845 us; speedup 1.0000x reference)
//
#include <hip/hip_runtime.h>
#include <hip/hip_bf16.h>
#include <cstddef>

// Problem constants
#define BATCH 32
#define TSTEPS 20
#define IN_DIM 3
#define WIDTH 256
#define HID 64
#define FC1_IN 327680   // HID * TSTEPS * WIDTH
#define FC1_OUT 512
#define OUT_DIM 3

typedef _Float16 half8 __attribute__((ext_vector_type(8)));
typedef _Float16 half4 __attribute__((ext_vector_type(4)));
typedef float floatx4 __attribute__((ext_vector_type(4)));

__device__ __forceinline__ float sigm(float x) {
    return 1.0f / (1.0f + __expf(-x));
}
__device__ __forceinline__ float tanh_fast(float x) {
    return 1.0f - 2.0f / (__expf(2.0f * x) + 1.0f);
}

// ---------------- prep kernels (once per launch) ----------------

// wt0[kw][co][ci'=96]: ci' 0..2 = x ch, 3..7 = 0, 8..71 = h ch (orig 3..66), 72..95 = 0.
__global__ __launch_bounds__(256) void prep_w0(
    const float* __restrict__ cw0, _Float16* __restrict__ wt0)
{
    int e = blockIdx.x * 256 + threadIdx.x;   // < 256*96
    if (e >= 256 * 96) return;
    int co = e / 96, cip = e - co * 96;
    int ci = -1;
    if (cip < 3) ci = cip;
    else if (cip >= 8 && cip < 72) ci = cip - 5;
    float v[3] = {0.f, 0.f, 0.f};
    if (ci >= 0) {
#pragma unroll
        for (int kw = 0; kw < 3; ++kw)
            v[kw] = cw0[(size_t)(co * 67 + ci) * 9 + 3 + kw];
    }
#pragma unroll
    for (int kw = 0; kw < 3; ++kw)
        wt0[(size_t)(kw * 256 + co) * 96 + cip] = (_Float16)v[kw];
}

// wt1[kw][co][ci=128]: direct (z = [h0 64 | h1 64] matches cw1 ci order).
__global__ __launch_bounds__(256) void prep_w1(
    const float* __restrict__ cw1, _Float16* __restrict__ wt1)
{
    int e = blockIdx.x * 256 + threadIdx.x;   // < 256*128
    int co = e >> 7, ci = e & 127;
#pragma unroll
    for (int kw = 0; kw < 3; ++kw)
        wt1[(size_t)(kw * 256 + co) * 128 + ci] =
            (_Float16)cw1[(size_t)(co * 128 + ci) * 9 + 3 + kw];
}

// xT[t][b][w][8] fp16: ch 0..2 from x[b][t][ch][w], 3..7 = 0.
__global__ __launch_bounds__(256) void prep_x(
    const float* __restrict__ x, _Float16* __restrict__ xT)
{
    int e = blockIdx.x * 256 + threadIdx.x;   // < 20*32*256
    if (e >= TSTEPS * BATCH * WIDTH) return;
    int t = e / (BATCH * WIDTH);
    int rem = e - t * BATCH * WIDTH;
    int b = rem >> 8, w = rem & 255;
    half8 v = {};
#pragma unroll
    for (int ci = 0; ci < 3; ++ci)
        v[ci] = (_Float16)x[(size_t)((b * TSTEPS + t) * IN_DIM + ci) * WIDTH + w];
    *(half8*)&xT[(size_t)e * 8] = v;
}

// ---------------- fused per-step kernel: layer0 + layer1 ----------------
// Grid (32 b, 8 wtiles of 32 cols), 512 threads = 8 waves = (w-half s) x (hc wv).
// Wave (s,wv) owns hc-slice [wv*16,+16) (all 4 gates: co = cf*64 + hc) and an
// n-half. Layer0 rows n=0..33 (w = w0-1+n): s=0 tiles {0,16} keep n in [0,16],
// s=1 tiles {17,33} keep n in [17,33] -> disjoint, full z1h coverage, no races.
// Layer1: tile base s*16 (16 owned rows each). Epilogues register-local.
// 2 barriers/step; 2 waves/SIMD for latency hiding.
__global__ __launch_bounds__(512) void conv2_step(
    const _Float16* __restrict__ xT,   // [t][b][w][8]
    const _Float16* __restrict__ wt0,  // [3][256][96]
    const _Float16* __restrict__ wt1,  // [3][256][128]
    const float* __restrict__ cb0,
    const float* __restrict__ cb1,
    const _Float16* __restrict__ h0p,  // [b][w][64] prev
    _Float16* __restrict__ h0n,
    const float* __restrict__ c0p,     // [b][w][64] prev
    float* __restrict__ c0n,
    const _Float16* __restrict__ h1p,
    _Float16* __restrict__ h1n,
    float* __restrict__ c1,            // in place
    _Float16* __restrict__ fcin,       // [b][(t*64+hc)*256+w] fp16
    int t)
{
    // z0h: rows j=0..51 (data rows 0..35, w = w0-2+j; rows 36..51 zero, read by
    // junk tail rows of s=1 tile base 33). 256B/row, XOR-swizzled 16B chunks.
    __shared__ __align__(16) _Float16 z0h[52 * 128];
    // z1h: rows j=0..33 (w = w0-1+j); chunks 0..7 = h0new (epilogue writes),
    // 8..15 = h1prev (staged).
    __shared__ __align__(16) _Float16 z1h[34 * 128];

    const int b     = blockIdx.x;
    const int wtile = blockIdx.y;
    const int w0    = wtile * 32;
    const int tid   = threadIdx.x;
    const int wave = tid >> 6;
    const int s  = wave & 1;     // n-half
    const int wv = wave >> 1;    // hc-slice
    const int ln = tid & 63;
    const int lr = ln & 15;
    const int kg = ln >> 4;
    const int hc = wv * 16 + lr;

    float cbr0[4], cbr1[4];
#pragma unroll
    for (int cf = 0; cf < 4; ++cf) {
        cbr0[cf] = cb0[cf * 64 + hc];
        cbr1[cf] = cb1[cf * 64 + hc];
    }

    // ---- stage z0 (chunks: 0=x, 1..8=h0prev, 9..11=pad) + zero tail rows
    for (int i = tid; i < 52 * 12; i += 512) {
        int j = i / 12, c = i - j * 12;
        int wg = w0 - 2 + j;
        half8 v = {};
        if (j < 36 && wg >= 0 && wg < WIDTH) {
            if (c == 0)
                v = *(const half8*)&xT[(size_t)((t * BATCH + b) * WIDTH + wg) * 8];
            else if (c <= 8)
                v = *(const half8*)&h0p[(size_t)(b * WIDTH + wg) * 64 + (c - 1) * 8];
        }
        int off = (j << 8) + ((c ^ (j & 7)) << 4);
        *(half8*)((char*)z0h + off) = v;
    }
    // ---- stage z1 chunks 8..15 = h1prev (rows j=0..33, w = w0-1+j)
    for (int i = tid; i < 34 * 8; i += 512) {
        int j = i >> 3, cc = i & 7;
        int wg = w0 - 1 + j;
        half8 v = {};
        if (wg >= 0 && wg < WIDTH)
            v = *(const half8*)&h1p[(size_t)(b * WIDTH + wg) * 64 + cc * 8];
        int c = cc + 8;
        int off = (j << 8) + ((c ^ (j & 7)) << 4);
        *(half8*)((char*)z1h + off) = v;
    }
    __syncthreads();

    // ---- layer0 MFMA: this wave: tiles base = s*17 + nf*16, co = cf*64 + hc
    floatx4 acc0[2][4];
#pragma unroll
    for (int nf = 0; nf < 2; ++nf)
#pragma unroll
        for (int cf = 0; cf < 4; ++cf) acc0[nf][cf] = (floatx4)0.0f;

#pragma unroll
    for (int kw = 0; kw < 3; ++kw)
#pragma unroll
    for (int kf = 0; kf < 3; ++kf) {
        half8 a[2];
#pragma unroll
        for (int nf = 0; nf < 2; ++nf) {
            int row = s * 17 + nf * 16 + lr + kw;   // max 33+15+2 = 50 < 52
            int slot = (kf * 4 + kg) ^ (row & 7);
            a[nf] = *(const half8*)((const char*)z0h + (row << 8) + (slot << 4));
        }
#pragma unroll
        for (int cf = 0; cf < 4; ++cf) {
            half8 bf = *(const half8*)&wt0[
                (size_t)(kw * 256 + cf * 64 + hc) * 96 + kf * 32 + kg * 8];
#pragma unroll
            for (int nf = 0; nf < 2; ++nf)
                acc0[nf][cf] = __builtin_amdgcn_mfma_f32_16x16x32_f16(a[nf], bf, acc0[nf][cf], 0, 0, 0);
        }
    }

    // ---- layer0 epilogue: register-local; keep n in [s?17:0, s?33:16]
    {
        const int nlo = s ? 17 : 0;
        const int nhi = s ? 33 : 16;
#pragma unroll
        for (int nf = 0; nf < 2; ++nf)
#pragma unroll
        for (int r = 0; r < 4; ++r) {
            int n = s * 17 + nf * 16 + kg * 4 + r;
            if (n < nlo || n > nhi) continue;
            int w = w0 - 1 + n;
            bool valid = (w >= 0) && (w < WIDTH);
            _Float16 hv = (_Float16)0.0f;
            if (valid) {
                size_t idx = (size_t)(b * WIDTH + w) * 64 + hc;
                float cin = c0p[idx];
                float cn = sigm(acc0[nf][1][r] + cbr0[1]) * cin
                         + sigm(acc0[nf][0][r] + cbr0[0]) * tanh_fast(acc0[nf][3][r] + cbr0[3]);
                hv = (_Float16)(sigm(acc0[nf][2][r] + cbr0[2]) * tanh_fast(cn));
                if (n >= 1 && n <= 32) {
                    c0n[idx] = cn;
                    h0n[idx] = hv;
                }
            }
            int c = hc >> 3;
            int off = (n << 8) + ((c ^ (n & 7)) << 4) + (hc & 7) * 2;
            *(_Float16*)((char*)z1h + off) = hv;
        }
    }
    __syncthreads();

    // ---- layer1 MFMA: tile base s*16, rows n=0..15 local
    floatx4 acc1[4];
#pragma unroll
    for (int cf = 0; cf < 4; ++cf) acc1[cf] = (floatx4)0.0f;

#pragma unroll
    for (int kw = 0; kw < 3; ++kw)
#pragma unroll
    for (int kf = 0; kf < 4; ++kf) {
        int row = s * 16 + lr + kw;     // max 16+15+2 = 33
        int slot = (kf * 4 + kg) ^ (row & 7);
        half8 a = *(const half8*)((const char*)z1h + (row << 8) + (slot << 4));
#pragma unroll
        for (int cf = 0; cf < 4; ++cf) {
            half8 bf = *(const half8*)&wt1[
                (size_t)(kw * 256 + cf * 64 + hc) * 128 + kf * 32 + kg * 8];
            acc1[cf] = __builtin_amdgcn_mfma_f32_16x16x32_f16(a, bf, acc1[cf], 0, 0, 0);
        }
    }

    // ---- layer1 epilogue: register-local; writes h1n, c1, fcin
#pragma unroll
    for (int r = 0; r < 4; ++r) {
        int n = s * 16 + kg * 4 + r;
        int w = w0 + n;
        size_t idx = (size_t)(b * WIDTH + w) * 64 + hc;
        float cin = c1[idx];
        float cn = sigm(acc1[1][r] + cbr1[1]) * cin
                 + sigm(acc1[0][r] + cbr1[0]) * tanh_fast(acc1[3][r] + cbr1[3]);
        _Float16 hv = (_Float16)(sigm(acc1[2][r] + cbr1[2]) * tanh_fast(cn));
        c1[idx] = cn;
        h1n[idx] = hv;
        fcin[(size_t)b * FC1_IN + (size_t)(t * HID + hc) * WIDTH + w] = hv;
    }
}

// ---------------- FC1 fp16 MFMA GEMM, K-split ----------------
#define KSLICE 1280
#define KPHASE 640
#define ALDS_STRIDE 648

__global__ __launch_bounds__(512) void fc1_mfma(
    const _Float16* __restrict__ a,   // fcin [32][327680] fp16
    const float* __restrict__ w,      // fc1_w [512][327680] fp32
    float* __restrict__ part)         // [256][512][32] fp32 partials
{
    __shared__ _Float16 alds[32][ALDS_STRIDE];

    const int blk = blockIdx.x;
    const int tid = threadIdx.x;
    const int wv  = tid >> 6;
    const int ln  = tid & 63;
    const int lg  = ln >> 4;
    const int lr  = ln & 15;
    const int k0  = blk * KSLICE;

    floatx4 acc[2][4];
#pragma unroll
    for (int bt = 0; bt < 2; ++bt)
#pragma unroll
        for (int nt = 0; nt < 4; ++nt) acc[bt][nt] = (floatx4)0.0f;

    const float* wbase[4];
#pragma unroll
    for (int nt = 0; nt < 4; ++nt)
        wbase[nt] = w + (size_t)(wv * 64 + nt * 16 + lr) * FC1_IN + k0 + lg * 8;

    for (int p = 0; p < 2; ++p) {
        __syncthreads();
        for (int i = tid; i < 32 * 80; i += 512) {
            int r = i / 80;
            int c = (i - r * 80) * 8;
            *(half8*)&alds[r][c] =
                *(const half8*)&a[(size_t)r * FC1_IN + k0 + p * KPHASE + c];
        }
        __syncthreads();

        for (int kc = 0; kc < KPHASE / 32; ++kc) {
            half8 af0 = *(const half8*)&alds[lr][kc * 32 + lg * 8];
            half8 af1 = *(const half8*)&alds[16 + lr][kc * 32 + lg * 8];
#pragma unroll
            for (int nt = 0; nt < 4; ++nt) {
                const float* wp = wbase[nt] + p * KPHASE + kc * 32;
                float4 wlo = *(const float4*)wp;
                float4 whi = *(const float4*)(wp + 4);
                half8 bf;
                bf[0] = (_Float16)wlo.x; bf[1] = (_Float16)wlo.y;
                bf[2] = (_Float16)wlo.z; bf[3] = (_Float16)wlo.w;
                bf[4] = (_Float16)whi.x; bf[5] = (_Float16)whi.y;
                bf[6] = (_Float16)whi.z; bf[7] = (_Float16)whi.w;
                acc[0][nt] = __builtin_amdgcn_mfma_f32_16x16x32_f16(af0, bf, acc[0][nt], 0, 0, 0);
                acc[1][nt] = __builtin_amdgcn_mfma_f32_16x16x32_f16(af1, bf, acc[1][nt], 0, 0, 0);
            }
        }
    }

#pragma unroll
    for (int bt = 0; bt < 2; ++bt)
#pragma unroll
        for (int nt = 0; nt < 4; ++nt) {
            int n = wv * 64 + nt * 16 + lr;
            int b = bt * 16 + lg * 4;
            *(float4*)&part[((size_t)blk * FC1_OUT + n) * BATCH + b] =
                *(float4*)&acc[bt][nt];
        }
}

__global__ __launch_bounds__(256) void fc1_reduce(
    const float* __restrict__ part, const float* __restrict__ b1,
    float* __restrict__ z1)
{
    int e = blockIdx.x * 256 + threadIdx.x;  // e = n*32 + b
    float s = 0.0f;
    for (int ks = 0; ks < 256; ++ks)
        s += part[(size_t)ks * (FC1_OUT * BATCH) + e];
    int n = e >> 5, b = e & 31;
    float v = s + b1[n];
    z1[(size_t)b * FC1_OUT + n] = v > 0.0f ? v : 0.0f;
}

__global__ __launch_bounds__(128) void fc2_kernel(
    const float* __restrict__ z1, const float* __restrict__ w2,
    const float* __restrict__ b2, float* __restrict__ out)
{
    int t = threadIdx.x;
    if (t >= BATCH * OUT_DIM) return;
    int b = t / OUT_DIM, n = t - b * OUT_DIM;
    const float* zr = z1 + (size_t)b * FC1_OUT;
    const float* wr = w2 + (size_t)n * FC1_OUT;
    float acc = b2[n];
    for (int k = 0; k < FC1_OUT; ++k) acc += zr[k] * wr[k];
    if (n == 2) acc = sigm(acc);
    out[(size_t)b * OUT_DIM + n] = acc;
}

extern "C" void kernel_launch(void* const* d_in, const int* in_sizes, int n_in,
                              void* d_out, int out_size, void* d_ws, size_t ws_size,
                              hipStream_t stream) {
    const float* x   = (const float*)d_in[0];
    const float* cw0 = (const float*)d_in[1];
    const float* cb0 = (const float*)d_in[2];
    const float* cw1 = (const float*)d_in[3];
    const float* cb1 = (const float*)d_in[4];
    const float* w1  = (const float*)d_in[5];
    const float* b1  = (const float*)d_in[6];
    const float* w2  = (const float*)d_in[7];
    const float* b2  = (const float*)d_in[8];
    float* out = (float*)d_out;

    const size_t S = (size_t)BATCH * WIDTH * HID;   // 524288 elements
    char* p = (char*)d_ws;
    auto alloc = [&](size_t bytes) { char* r = p; p += (bytes + 255) & ~(size_t)255; return r; };

    // zero block first (read at t=0): h0a, h1a, c0a, c1
    _Float16* h0a = (_Float16*)alloc(S * 2);
    _Float16* h1a = (_Float16*)alloc(S * 2);
    float*    c0a = (float*)alloc(S * 4);
    float*    c1  = (float*)alloc(S * 4);
    size_t zero_bytes = (size_t)(p - (char*)d_ws);

    _Float16* h0b = (_Float16*)alloc(S * 2);
    _Float16* h1b = (_Float16*)alloc(S * 2);
    float*    c0b = (float*)alloc(S * 4);
    _Float16* wt0 = (_Float16*)alloc((size_t)3 * 256 * 96 * 2);
    _Float16* wt1 = (_Float16*)alloc((size_t)3 * 256 * 128 * 2);
    _Float16* xT  = (_Float16*)alloc((size_t)TSTEPS * BATCH * WIDTH * 8 * 2);
    _Float16* fcin = (_Float16*)alloc((size_t)BATCH * FC1_IN * 2);
    float* part = (float*)alloc((size_t)256 * FC1_OUT * BATCH * 4);
    float* z1   = (float*)alloc((size_t)BATCH * FC1_OUT * 4);

    hipMemsetAsync(d_ws, 0, zero_bytes, stream);
    prep_w0<<<96, 256, 0, stream>>>(cw0, wt0);
    prep_w1<<<128, 256, 0, stream>>>(cw1, wt1);
    prep_x<<<(TSTEPS * BATCH * WIDTH + 255) / 256, 256, 0, stream>>>(x, xT);

    dim3 cgrid(BATCH, 8);
    for (int t = 0; t < TSTEPS; ++t) {
        const _Float16* h0r = (t & 1) ? h0b : h0a;
        _Float16*       h0w = (t & 1) ? h0a : h0b;
        const float*    c0r = (t & 1) ? c0b : c0a;
        float*          c0w = (t & 1) ? c0a : c0b;
        const _Float16* h1r = (t & 1) ? h1b : h1a;
        _Float16*       h1w = (t & 1) ? h1a : h1b;
        conv2_step<<<cgrid, 512, 0, stream>>>(
            xT, wt0, wt1, cb0, cb1,
            h0r, h0w, c0r, c0w, h1r, h1w, c1, fcin, t);
    }

    fc1_mfma<<<256, 512, 0, stream>>>(fcin, w1, part);
    fc1_reduce<<<64, 256, 0, stream>>>(part, b1, z1);
    fc2_kernel<<<1, 128, 0, stream>>>(z1, w2, b2, out);
}

// Round 8
// 496.693 us; speedup vs baseline: 1.2359x; 1.2359x over previous
//
#include <hip/hip_runtime.h>
#include <hip/hip_bf16.h>
#include <cstddef>

// Problem constants
#define BATCH 32
#define TSTEPS 20
#define IN_DIM 3
#define WIDTH 256
#define HID 64
#define FC1_IN 327680   // HID * TSTEPS * WIDTH
#define FC1_OUT 512
#define OUT_DIM 3

typedef _Float16 half8 __attribute__((ext_vector_type(8)));
typedef _Float16 half4 __attribute__((ext_vector_type(4)));
typedef float floatx4 __attribute__((ext_vector_type(4)));

__device__ __forceinline__ float sigm(float x) {
    return 1.0f / (1.0f + __expf(-x));
}
__device__ __forceinline__ float tanh_fast(float x) {
    return 1.0f - 2.0f / (__expf(2.0f * x) + 1.0f);
}

// ---------------- prep kernels (once per launch) ----------------

// wt0[kw][co][ci'=96]: ci' 0..2 = x ch, 3..7 = 0, 8..71 = h ch (orig 3..66), 72..95 = 0.
__global__ __launch_bounds__(256) void prep_w0(
    const float* __restrict__ cw0, _Float16* __restrict__ wt0)
{
    int e = blockIdx.x * 256 + threadIdx.x;   // < 256*96
    if (e >= 256 * 96) return;
    int co = e / 96, cip = e - co * 96;
    int ci = -1;
    if (cip < 3) ci = cip;
    else if (cip >= 8 && cip < 72) ci = cip - 5;
    float v[3] = {0.f, 0.f, 0.f};
    if (ci >= 0) {
#pragma unroll
        for (int kw = 0; kw < 3; ++kw)
            v[kw] = cw0[(size_t)(co * 67 + ci) * 9 + 3 + kw];
    }
#pragma unroll
    for (int kw = 0; kw < 3; ++kw)
        wt0[(size_t)(kw * 256 + co) * 96 + cip] = (_Float16)v[kw];
}

// wt1[kw][co][ci=128]: direct (z = [h0 64 | h1 64] matches cw1 ci order).
__global__ __launch_bounds__(256) void prep_w1(
    const float* __restrict__ cw1, _Float16* __restrict__ wt1)
{
    int e = blockIdx.x * 256 + threadIdx.x;   // < 256*128
    int co = e >> 7, ci = e & 127;
#pragma unroll
    for (int kw = 0; kw < 3; ++kw)
        wt1[(size_t)(kw * 256 + co) * 128 + ci] =
            (_Float16)cw1[(size_t)(co * 128 + ci) * 9 + 3 + kw];
}

// xT[t][b][w][8] fp16: ch 0..2 from x[b][t][ch][w], 3..7 = 0.
__global__ __launch_bounds__(256) void prep_x(
    const float* __restrict__ x, _Float16* __restrict__ xT)
{
    int e = blockIdx.x * 256 + threadIdx.x;   // < 20*32*256
    if (e >= TSTEPS * BATCH * WIDTH) return;
    int t = e / (BATCH * WIDTH);
    int rem = e - t * BATCH * WIDTH;
    int b = rem >> 8, w = rem & 255;
    half8 v = {};
#pragma unroll
    for (int ci = 0; ci < 3; ++ci)
        v[ci] = (_Float16)x[(size_t)((b * TSTEPS + t) * IN_DIM + ci) * WIDTH + w];
    *(half8*)&xT[(size_t)e * 8] = v;
}

// ---------------- fused per-step kernel: wave-specialized ----------------
// Grid (32 b, 8 wtiles of 32 cols), 512 threads = 8 waves.
// Waves 0-3 = layer0 (hc-slice wv*16, all 4 gates); waves 4-7 = layer1.
// Each group burst-loads its B operand into REGISTERS at kernel start
// (L0: 36 half8 = 144 VGPR, L1: 48 half8 = 192 VGPR) -> MFMA phases have no
// global-latency loads. Single if/else, 2 barriers in each branch (equal
// per-wave barrier counts = valid producer/consumer pattern on CDNA).
// Layer0 computes 34 cols (1-col redundant halo each side, bit-identical to
// neighbor's); h0 -> z1h in LDS; epilogues register-local (c prefetched).
__global__ __launch_bounds__(512) void conv2_step(
    const _Float16* __restrict__ xT,   // [t][b][w][8]
    const _Float16* __restrict__ wt0,  // [3][256][96]
    const _Float16* __restrict__ wt1,  // [3][256][128]
    const float* __restrict__ cb0,
    const float* __restrict__ cb1,
    const _Float16* __restrict__ h0p,  // [b][w][64] prev
    _Float16* __restrict__ h0n,
    const float* __restrict__ c0p,     // [b][w][64] prev
    float* __restrict__ c0n,
    const _Float16* __restrict__ h1p,
    _Float16* __restrict__ h1n,
    float* __restrict__ c1,            // in place
    _Float16* __restrict__ fcin,       // [b][(t*64+hc)*256+w] fp16
    int t)
{
    // z0h rows j=0..49 (data rows 0..35, w = w0-2+j; rows 36..49 zero, read by
    // junk tail of tile 2). 256B/row, XOR-swizzled 16B chunks (slot = c^(j&7)).
    __shared__ __align__(16) _Float16 z0h[50 * 128];
    // z1h rows j=0..33 (w = w0-1+j); chunks 0..7 = h0new, 8..15 = h1prev.
    __shared__ __align__(16) _Float16 z1h[34 * 128];

    const int b     = blockIdx.x;
    const int wtile = blockIdx.y;
    const int w0    = wtile * 32;
    const int tid   = threadIdx.x;
    const int wave  = tid >> 6;
    const int ln = tid & 63;
    const int lr = ln & 15;
    const int kg = ln >> 4;

    if (wave < 4) {
        // ================= LAYER-0 WAVES =================
        const int hc = wave * 16 + lr;

        // burst-load B0 into registers (36 x 16B per lane, independent)
        half8 b0r[3][3][4];
#pragma unroll
        for (int kw = 0; kw < 3; ++kw)
#pragma unroll
        for (int kf = 0; kf < 3; ++kf)
#pragma unroll
        for (int cf = 0; cf < 4; ++cf)
            b0r[kw][kf][cf] = *(const half8*)&wt0[
                (size_t)(kw * 256 + cf * 64 + hc) * 96 + kf * 32 + kg * 8];

        // prefetch c0p for this lane's epilogue elements
        float c0pre[3][4];
#pragma unroll
        for (int j = 0; j < 3; ++j)
#pragma unroll
        for (int r = 0; r < 4; ++r) {
            int n = 16 * j + kg * 4 + r;
            int w = w0 - 1 + n;
            c0pre[j][r] = (n < 34 && w >= 0 && w < WIDTH)
                ? c0p[(size_t)(b * WIDTH + w) * 64 + hc] : 0.0f;
        }

        float cbr0[4];
#pragma unroll
        for (int cf = 0; cf < 4; ++cf) cbr0[cf] = cb0[cf * 64 + hc];

        // stage z0h (chunks: 0=x, 1..8=h0prev, 9..11=pad) + zero tail rows
        for (int i = tid; i < 50 * 12; i += 256) {
            int j = i / 12, c = i - j * 12;
            int wg = w0 - 2 + j;
            half8 v = {};
            if (j < 36 && wg >= 0 && wg < WIDTH) {
                if (c == 0)
                    v = *(const half8*)&xT[(size_t)((t * BATCH + b) * WIDTH + wg) * 8];
                else if (c <= 8)
                    v = *(const half8*)&h0p[(size_t)(b * WIDTH + wg) * 64 + (c - 1) * 8];
            }
            int off = (j << 8) + ((c ^ (j & 7)) << 4);
            *(half8*)((char*)z0h + off) = v;
        }
        __syncthreads();   // barrier 1: z staged

        // MFMA0 + epilogue, tile-sequential (B from regs, A from LDS)
#pragma unroll
        for (int j = 0; j < 3; ++j) {
            floatx4 acc[4];
#pragma unroll
            for (int cf = 0; cf < 4; ++cf) acc[cf] = (floatx4)0.0f;
#pragma unroll
            for (int kw = 0; kw < 3; ++kw)
#pragma unroll
            for (int kf = 0; kf < 3; ++kf) {
                int row = 16 * j + lr + kw;
                int slot = (kf * 4 + kg) ^ (row & 7);
                half8 a = *(const half8*)((const char*)z0h + (row << 8) + (slot << 4));
#pragma unroll
                for (int cf = 0; cf < 4; ++cf)
                    acc[cf] = __builtin_amdgcn_mfma_f32_16x16x32_f16(a, b0r[kw][kf][cf], acc[cf], 0, 0, 0);
            }
            // register-local epilogue: thread owns (n = 16j + kg*4 + r, hc)
#pragma unroll
            for (int r = 0; r < 4; ++r) {
                int n = 16 * j + kg * 4 + r;
                if (n >= 34) continue;
                int w = w0 - 1 + n;
                bool valid = (w >= 0) && (w < WIDTH);
                _Float16 hv = (_Float16)0.0f;
                if (valid) {
                    size_t idx = (size_t)(b * WIDTH + w) * 64 + hc;
                    float cn = sigm(acc[1][r] + cbr0[1]) * c0pre[j][r]
                             + sigm(acc[0][r] + cbr0[0]) * tanh_fast(acc[3][r] + cbr0[3]);
                    hv = (_Float16)(sigm(acc[2][r] + cbr0[2]) * tanh_fast(cn));
                    if (n >= 1 && n <= 32) {
                        c0n[idx] = cn;
                        h0n[idx] = hv;
                    }
                }
                int c = hc >> 3;
                int off = (n << 8) + ((c ^ (n & 7)) << 4) + (hc & 7) * 2;
                *(_Float16*)((char*)z1h + off) = hv;
            }
        }
        __syncthreads();   // barrier 2: z1h h0-part complete
        // layer-0 waves done
    } else {
        // ================= LAYER-1 WAVES =================
        const int hc = (wave - 4) * 16 + lr;

        // burst-load B1 into registers (48 x 16B per lane)
        half8 b1r[3][4][4];
#pragma unroll
        for (int kw = 0; kw < 3; ++kw)
#pragma unroll
        for (int kf = 0; kf < 4; ++kf)
#pragma unroll
        for (int cf = 0; cf < 4; ++cf)
            b1r[kw][kf][cf] = *(const half8*)&wt1[
                (size_t)(kw * 256 + cf * 64 + hc) * 128 + kf * 32 + kg * 8];

        // prefetch c1 (owned cols, always valid)
        float c1pre[2][4];
#pragma unroll
        for (int j = 0; j < 2; ++j)
#pragma unroll
        for (int r = 0; r < 4; ++r) {
            int n = 16 * j + kg * 4 + r;
            c1pre[j][r] = c1[(size_t)(b * WIDTH + w0 + n) * 64 + hc];
        }

        float cbr1[4];
#pragma unroll
        for (int cf = 0; cf < 4; ++cf) cbr1[cf] = cb1[cf * 64 + hc];

        // stage z1h chunks 8..15 = h1prev (rows j=0..33, w = w0-1+j)
        for (int i = tid - 256; i < 34 * 8; i += 256) {
            int j = i >> 3, cc = i & 7;
            int wg = w0 - 1 + j;
            half8 v = {};
            if (wg >= 0 && wg < WIDTH)
                v = *(const half8*)&h1p[(size_t)(b * WIDTH + wg) * 64 + cc * 8];
            int c = cc + 8;
            int off = (j << 8) + ((c ^ (j & 7)) << 4);
            *(half8*)((char*)z1h + off) = v;
        }
        __syncthreads();   // barrier 1
        // (layer0 computing)
        __syncthreads();   // barrier 2: z1h ready

        // MFMA1 + epilogue
#pragma unroll
        for (int j = 0; j < 2; ++j) {
            floatx4 acc[4];
#pragma unroll
            for (int cf = 0; cf < 4; ++cf) acc[cf] = (floatx4)0.0f;
#pragma unroll
            for (int kw = 0; kw < 3; ++kw)
#pragma unroll
            for (int kf = 0; kf < 4; ++kf) {
                int row = 16 * j + lr + kw;     // max 33
                int slot = (kf * 4 + kg) ^ (row & 7);
                half8 a = *(const half8*)((const char*)z1h + (row << 8) + (slot << 4));
#pragma unroll
                for (int cf = 0; cf < 4; ++cf)
                    acc[cf] = __builtin_amdgcn_mfma_f32_16x16x32_f16(a, b1r[kw][kf][cf], acc[cf], 0, 0, 0);
            }
#pragma unroll
            for (int r = 0; r < 4; ++r) {
                int n = 16 * j + kg * 4 + r;
                int w = w0 + n;
                size_t idx = (size_t)(b * WIDTH + w) * 64 + hc;
                float cn = sigm(acc[1][r] + cbr1[1]) * c1pre[j][r]
                         + sigm(acc[0][r] + cbr1[0]) * tanh_fast(acc[3][r] + cbr1[3]);
                _Float16 hv = (_Float16)(sigm(acc[2][r] + cbr1[2]) * tanh_fast(cn));
                c1[idx] = cn;
                h1n[idx] = hv;
                fcin[(size_t)b * FC1_IN + (size_t)(t * HID + hc) * WIDTH + w] = hv;
            }
        }
    }
}

// ---------------- FC1 fp16 MFMA GEMM, K-split ----------------
#define KSLICE 1280
#define KPHASE 640
#define ALDS_STRIDE 648

__global__ __launch_bounds__(512) void fc1_mfma(
    const _Float16* __restrict__ a,   // fcin [32][327680] fp16
    const float* __restrict__ w,      // fc1_w [512][327680] fp32
    float* __restrict__ part)         // [256][512][32] fp32 partials
{
    __shared__ _Float16 alds[32][ALDS_STRIDE];

    const int blk = blockIdx.x;
    const int tid = threadIdx.x;
    const int wv  = tid >> 6;
    const int ln  = tid & 63;
    const int lg  = ln >> 4;
    const int lr  = ln & 15;
    const int k0  = blk * KSLICE;

    floatx4 acc[2][4];
#pragma unroll
    for (int bt = 0; bt < 2; ++bt)
#pragma unroll
        for (int nt = 0; nt < 4; ++nt) acc[bt][nt] = (floatx4)0.0f;

    const float* wbase[4];
#pragma unroll
    for (int nt = 0; nt < 4; ++nt)
        wbase[nt] = w + (size_t)(wv * 64 + nt * 16 + lr) * FC1_IN + k0 + lg * 8;

    for (int p = 0; p < 2; ++p) {
        __syncthreads();
        for (int i = tid; i < 32 * 80; i += 512) {
            int r = i / 80;
            int c = (i - r * 80) * 8;
            *(half8*)&alds[r][c] =
                *(const half8*)&a[(size_t)r * FC1_IN + k0 + p * KPHASE + c];
        }
        __syncthreads();

        for (int kc = 0; kc < KPHASE / 32; ++kc) {
            half8 af0 = *(const half8*)&alds[lr][kc * 32 + lg * 8];
            half8 af1 = *(const half8*)&alds[16 + lr][kc * 32 + lg * 8];
#pragma unroll
            for (int nt = 0; nt < 4; ++nt) {
                const float* wp = wbase[nt] + p * KPHASE + kc * 32;
                float4 wlo = *(const float4*)wp;
                float4 whi = *(const float4*)(wp + 4);
                half8 bf;
                bf[0] = (_Float16)wlo.x; bf[1] = (_Float16)wlo.y;
                bf[2] = (_Float16)wlo.z; bf[3] = (_Float16)wlo.w;
                bf[4] = (_Float16)whi.x; bf[5] = (_Float16)whi.y;
                bf[6] = (_Float16)whi.z; bf[7] = (_Float16)whi.w;
                acc[0][nt] = __builtin_amdgcn_mfma_f32_16x16x32_f16(af0, bf, acc[0][nt], 0, 0, 0);
                acc[1][nt] = __builtin_amdgcn_mfma_f32_16x16x32_f16(af1, bf, acc[1][nt], 0, 0, 0);
            }
        }
    }

#pragma unroll
    for (int bt = 0; bt < 2; ++bt)
#pragma unroll
        for (int nt = 0; nt < 4; ++nt) {
            int n = wv * 64 + nt * 16 + lr;
            int b = bt * 16 + lg * 4;
            *(float4*)&part[((size_t)blk * FC1_OUT + n) * BATCH + b] =
                *(float4*)&acc[bt][nt];
        }
}

__global__ __launch_bounds__(256) void fc1_reduce(
    const float* __restrict__ part, const float* __restrict__ b1,
    float* __restrict__ z1)
{
    int e = blockIdx.x * 256 + threadIdx.x;  // e = n*32 + b
    float s = 0.0f;
    for (int ks = 0; ks < 256; ++ks)
        s += part[(size_t)ks * (FC1_OUT * BATCH) + e];
    int n = e >> 5, b = e & 31;
    float v = s + b1[n];
    z1[(size_t)b * FC1_OUT + n] = v > 0.0f ? v : 0.0f;
}

__global__ __launch_bounds__(128) void fc2_kernel(
    const float* __restrict__ z1, const float* __restrict__ w2,
    const float* __restrict__ b2, float* __restrict__ out)
{
    int t = threadIdx.x;
    if (t >= BATCH * OUT_DIM) return;
    int b = t / OUT_DIM, n = t - b * OUT_DIM;
    const float* zr = z1 + (size_t)b * FC1_OUT;
    const float* wr = w2 + (size_t)n * FC1_OUT;
    float acc = b2[n];
    for (int k = 0; k < FC1_OUT; ++k) acc += zr[k] * wr[k];
    if (n == 2) acc = sigm(acc);
    out[(size_t)b * OUT_DIM + n] = acc;
}

extern "C" void kernel_launch(void* const* d_in, const int* in_sizes, int n_in,
                              void* d_out, int out_size, void* d_ws, size_t ws_size,
                              hipStream_t stream) {
    const float* x   = (const float*)d_in[0];
    const float* cw0 = (const float*)d_in[1];
    const float* cb0 = (const float*)d_in[2];
    const float* cw1 = (const float*)d_in[3];
    const float* cb1 = (const float*)d_in[4];
    const float* w1  = (const float*)d_in[5];
    const float* b1  = (const float*)d_in[6];
    const float* w2  = (const float*)d_in[7];
    const float* b2  = (const float*)d_in[8];
    float* out = (float*)d_out;

    const size_t S = (size_t)BATCH * WIDTH * HID;   // 524288 elements
    char* p = (char*)d_ws;
    auto alloc = [&](size_t bytes) { char* r = p; p += (bytes + 255) & ~(size_t)255; return r; };

    // zero block first (read at t=0): h0a, h1a, c0a, c1
    _Float16* h0a = (_Float16*)alloc(S * 2);
    _Float16* h1a = (_Float16*)alloc(S * 2);
    float*    c0a = (float*)alloc(S * 4);
    float*    c1  = (float*)alloc(S * 4);
    size_t zero_bytes = (size_t)(p - (char*)d_ws);

    _Float16* h0b = (_Float16*)alloc(S * 2);
    _Float16* h1b = (_Float16*)alloc(S * 2);
    float*    c0b = (float*)alloc(S * 4);
    _Float16* wt0 = (_Float16*)alloc((size_t)3 * 256 * 96 * 2);
    _Float16* wt1 = (_Float16*)alloc((size_t)3 * 256 * 128 * 2);
    _Float16* xT  = (_Float16*)alloc((size_t)TSTEPS * BATCH * WIDTH * 8 * 2);
    _Float16* fcin = (_Float16*)alloc((size_t)BATCH * FC1_IN * 2);
    float* part = (float*)alloc((size_t)256 * FC1_OUT * BATCH * 4);
    float* z1   = (float*)alloc((size_t)BATCH * FC1_OUT * 4);

    hipMemsetAsync(d_ws, 0, zero_bytes, stream);
    prep_w0<<<96, 256, 0, stream>>>(cw0, wt0);
    prep_w1<<<128, 256, 0, stream>>>(cw1, wt1);
    prep_x<<<(TSTEPS * BATCH * WIDTH + 255) / 256, 256, 0, stream>>>(x, xT);

    dim3 cgrid(BATCH, 8);
    for (int t = 0; t < TSTEPS; ++t) {
        const _Float16* h0r = (t & 1) ? h0b : h0a;
        _Float16*       h0w = (t & 1) ? h0a : h0b;
        const float*    c0r = (t & 1) ? c0b : c0a;
        float*          c0w = (t & 1) ? c0a : c0b;
        const _Float16* h1r = (t & 1) ? h1b : h1a;
        _Float16*       h1w = (t & 1) ? h1a : h1b;
        conv2_step<<<cgrid, 512, 0, stream>>>(
            xT, wt0, wt1, cb0, cb1,
            h0r, h0w, c0r, c0w, h1r, h1w, c1, fcin, t);
    }

    fc1_mfma<<<256, 512, 0, stream>>>(fcin, w1, part);
    fc1_reduce<<<64, 256, 0, stream>>>(part, b1, z1);
    fc2_kernel<<<1, 128, 0, stream>>>(z1, w2, b2, out);
}